// Round 9
// baseline (314.885 us; speedup 1.0000x reference)
//
#include <hip/hip_runtime.h>
#include <hip/hip_bf16.h>
#include <math.h>

#define NN 50000
#define EE 800000
#define FIN 256
#define HID 64
#define OUTD 64
#define H1 4
#define H2 1

typedef __attribute__((ext_vector_type(8))) short short8;
typedef __attribute__((ext_vector_type(4))) short short4v;
typedef __attribute__((ext_vector_type(4))) float f32x4;
typedef __attribute__((ext_vector_type(2))) float f32x2;

// ---------------- helpers ----------------

__device__ __forceinline__ unsigned short f2bf(float f) {   // round-to-nearest-even
    unsigned u = __float_as_uint(f);
    unsigned r = (u + 0x7FFFu + ((u >> 16) & 1u)) >> 16;
    return (unsigned short)r;
}
__device__ __forceinline__ float bf2f(unsigned short u) {
    return __uint_as_float(((unsigned)u) << 16);
}

// ---------------- CSR build ----------------
// hist + weight split fused (independent work, one launch)

__global__ void hist_wsplit(const int* __restrict__ dst, int* __restrict__ deg, int nE,
                            const float* __restrict__ W1, const float* __restrict__ W2,
                            short* __restrict__ W1th, short* __restrict__ W1tl,
                            short* __restrict__ W2th, short* __restrict__ W2tl) {
    int e = blockIdx.x * 256 + threadIdx.x;
    if (e < nE) atomicAdd(&deg[dst[e]], 1);
    int n = blockIdx.x;
    int k = threadIdx.x;
    if (n < 256) {
        float v = W1[(size_t)k * 256 + n];
        unsigned short hi = f2bf(v);
        unsigned short lo = f2bf(v - bf2f(hi));
        W1th[n * 256 + k] = (short)hi;
        W1tl[n * 256 + k] = (short)lo;
    } else if (n < 320) {
        int n2 = n - 256;
        float v = W2[(size_t)k * 64 + n2];
        unsigned short hi = f2bf(v);
        unsigned short lo = f2bf(v - bf2f(hi));
        W2th[n2 * 256 + k] = (short)hi;
        W2tl[n2 * 256 + k] = (short)lo;
    }
}

// single-block exclusive scan of deg[0..NN) -> rowptr, rowptr[NN]=EE
#define SCAN_CH 49
__global__ __launch_bounds__(1024) void scan_one(const int* __restrict__ deg,
                                                 int* __restrict__ rowptr) {
    __shared__ int wsum[16];
    int tid = threadIdx.x;
    int lane = tid & 63;
    int base = tid * SCAN_CH;
    int loc[SCAN_CH];
    int tot = 0;
#pragma unroll
    for (int j = 0; j < SCAN_CH; ++j) {
        int idx = base + j;
        int v = (idx < NN) ? deg[idx] : 0;
        loc[j] = tot;            // exclusive within chunk
        tot += v;
    }
    int incl = tot;
#pragma unroll
    for (int off = 1; off < 64; off <<= 1) {
        int t = __shfl_up(incl, off);
        if (lane >= off) incl += t;
    }
    if (lane == 63) wsum[tid >> 6] = incl;
    __syncthreads();
    if (tid == 0) {
        int run = 0;
#pragma unroll
        for (int i = 0; i < 16; ++i) { int t = wsum[i]; wsum[i] = run; run += t; }
    }
    __syncthreads();
    int excl = wsum[tid >> 6] + incl - tot;
#pragma unroll
    for (int j = 0; j < SCAN_CH; ++j) {
        int idx = base + j;
        if (idx < NN) rowptr[idx] = excl + loc[j];
    }
    if (tid == 0) rowptr[NN] = EE;
}

__global__ void fill_csr(const int* __restrict__ src, const int* __restrict__ dst,
                         const int* __restrict__ rowptr, int* __restrict__ fillc,
                         int* __restrict__ csr_src, int nE) {
    int e = blockIdx.x * 256 + threadIdx.x;
    if (e < nE) {
        int d = dst[e];
        int pos = rowptr[d] + atomicAdd(&fillc[d], 1);
        csr_src[pos] = src[e];
    }
}

// ---------------- MFMA GEMM + fused scores epilogue ----------
// ASPLIT=true : A f32, split to hi/lo in staging, 3 MFMA passes.
// ASPLIT=false: A already bf16 (exact), 2 MFMA passes.

template<int MF, int WR, int WC, int NT, int H, bool ASPLIT>
__global__ __launch_bounds__(256) void gemm_bf16x2(
    const void* __restrict__ Av, const short* __restrict__ Bth, const short* __restrict__ Btl,
    const float* __restrict__ al, const float* __restrict__ ar,
    unsigned short* __restrict__ zb, float* __restrict__ el, float* __restrict__ er,
    int M, int K)
{
    constexpr int BM = WR * MF * 16;
    constexpr int BN = WC * 64;
    __shared__ short Ah[BM * 40];
    __shared__ short Al[ASPLIT ? BM * 40 : 8];
    __shared__ short Bh[BN * 40], Bl[BN * 40];

    const int bm = blockIdx.x * BM;
    const int bn = blockIdx.y * BN;
    const int t = threadIdx.x;
    const int wid = t >> 6;
    const int lane = t & 63;
    const int lr = lane & 15;
    const int lg = lane >> 4;
    const int wr = wid / WC;
    const int wc = wid % WC;

    f32x4 acc[MF][4];
#pragma unroll
    for (int mf = 0; mf < MF; ++mf)
#pragma unroll
        for (int nf = 0; nf < 4; ++nf) acc[mf][nf] = (f32x4)(0.f);

    for (int k0 = 0; k0 < K; k0 += 32) {
        if constexpr (ASPLIT) {
            const float* A = (const float*)Av;
#pragma unroll
            for (int q = 0; q < BM / 32; ++q) {
                int linear = q * 256 + t;
                int row = linear >> 3;
                int kq = (linear & 7) * 4;
                int grow = bm + row;
                float4 av = make_float4(0.f, 0.f, 0.f, 0.f);
                if (grow < M) av = *(const float4*)(A + (size_t)grow * K + k0 + kq);
                short4v hi, lo;
                unsigned short h0 = f2bf(av.x); hi.x = (short)h0; lo.x = (short)f2bf(av.x - bf2f(h0));
                unsigned short h1v = f2bf(av.y); hi.y = (short)h1v; lo.y = (short)f2bf(av.y - bf2f(h1v));
                unsigned short h2v = f2bf(av.z); hi.z = (short)h2v; lo.z = (short)f2bf(av.z - bf2f(h2v));
                unsigned short h3v = f2bf(av.w); hi.w = (short)h3v; lo.w = (short)f2bf(av.w - bf2f(h3v));
                *(short4v*)&Ah[row * 40 + kq] = hi;
                *(short4v*)&Al[row * 40 + kq] = lo;
            }
        } else {
            const unsigned short* A = (const unsigned short*)Av;
#pragma unroll
            for (int q = 0; q < BM / 64; ++q) {
                int linear = q * 256 + t;
                int row = linear >> 2;
                int k8 = (linear & 3) * 8;
                int grow = bm + row;
                short8 v = (short8)(0);
                if (grow < M) v = *(const short8*)(A + (size_t)grow * K + k0 + k8);
                *(short8*)&Ah[row * 40 + k8] = v;
            }
        }
#pragma unroll
        for (int q = 0; q < BN / 64; ++q) {
            int linear = q * 256 + t;
            int n = linear >> 2;
            int k8 = (linear & 3) * 8;
            short8 vh = *(const short8*)(Bth + (size_t)(bn + n) * K + k0 + k8);
            short8 vl = *(const short8*)(Btl + (size_t)(bn + n) * K + k0 + k8);
            *(short8*)&Bh[n * 40 + k8] = vh;
            *(short8*)&Bl[n * 40 + k8] = vl;
        }
        __syncthreads();

        short8 bh[4], blo[4];
#pragma unroll
        for (int nf = 0; nf < 4; ++nf) {
            int col = wc * 64 + nf * 16 + lr;
            bh[nf]  = *(const short8*)&Bh[col * 40 + lg * 8];
            blo[nf] = *(const short8*)&Bl[col * 40 + lg * 8];
        }
#pragma unroll
        for (int mf = 0; mf < MF; ++mf) {
            int row = wr * MF * 16 + mf * 16 + lr;
            short8 ah = *(const short8*)&Ah[row * 40 + lg * 8];
            short8 alo;
            if constexpr (ASPLIT) alo = *(const short8*)&Al[row * 40 + lg * 8];
#pragma unroll
            for (int nf = 0; nf < 4; ++nf) {
                acc[mf][nf] = __builtin_amdgcn_mfma_f32_16x16x32_bf16(ah, bh[nf],  acc[mf][nf], 0, 0, 0);
                acc[mf][nf] = __builtin_amdgcn_mfma_f32_16x16x32_bf16(ah, blo[nf], acc[mf][nf], 0, 0, 0);
                if constexpr (ASPLIT)
                    acc[mf][nf] = __builtin_amdgcn_mfma_f32_16x16x32_bf16(alo, bh[nf], acc[mf][nf], 0, 0, 0);
            }
        }
        __syncthreads();
    }

    // ---- epilogue: zb (bf16) + el/er ----
    const int h = (bn + wc * 64) >> 6;
    float alv[4], arv[4];
#pragma unroll
    for (int nf = 0; nf < 4; ++nf) {
        alv[nf] = al[h * 64 + nf * 16 + lr];
        arv[nf] = ar[h * 64 + nf * 16 + lr];
    }
#pragma unroll
    for (int mf = 0; mf < MF; ++mf) {
#pragma unroll
        for (int j = 0; j < 4; ++j) {
            int row = bm + wr * MF * 16 + mf * 16 + lg * 4 + j;
            float sel = 0.f, ser = 0.f;
#pragma unroll
            for (int nf = 0; nf < 4; ++nf) {
                float v = acc[mf][nf][j];
                sel += v * alv[nf];
                ser += v * arv[nf];
                if (row < M)
                    zb[(size_t)row * NT + bn + wc * 64 + nf * 16 + lr] = f2bf(v);
            }
#pragma unroll
            for (int off = 1; off <= 8; off <<= 1) {
                sel += __shfl_xor(sel, off);
                ser += __shfl_xor(ser, off);
            }
            if (lr == 0 && row < M) {
                el[(size_t)row * H + h] = sel;
                er[(size_t)row * H + h] = ser;
            }
        }
    }
}

// ---------------- layer-1 aggregate (r7 structure: best measured) ----------------
// One wave per node, 4 heads merged; lane owns 8B (4 channels, head lane>>4);
// batches of 8 edges: 8 offsets+weights, 8 loads in flight, packed FMAs.

__global__ __launch_bounds__(256) void gat_aggregate_h4(
    const unsigned short* __restrict__ zb,   // [N,256] bf16
    const float* __restrict__ el,            // [N,4]
    const float* __restrict__ er,            // [N,4]
    const int* __restrict__ rowptr, const int* __restrict__ csr_src,
    const float* __restrict__ bias,          // [256]
    unsigned short* __restrict__ out,        // [N,256] bf16 (ELU applied)
    int Nn)
{
    __shared__ float p_lds[4][64][4];
    __shared__ int   s_lds[4][64];
    int wid = threadIdx.x >> 6;
    int lane = threadIdx.x & 63;
    int n = blockIdx.x * 4 + wid;
    if (n >= Nn) return;
    int start = rowptr[n], end = rowptr[n + 1];
    int deg = end - start;
    float4 er4 = *(const float4*)(er + (size_t)n * 4);
    int hsel = lane >> 4;
    const unsigned lb = (unsigned)(lane << 3);   // byte offset of this lane in a 512B row

    f32x2 acc01 = {0.f, 0.f}, acc23 = {0.f, 0.f};
    float4 ssum = make_float4(0.f, 0.f, 0.f, 0.f);
    float m = -INFINITY;

    for (int c0 = 0; c0 < deg; c0 += 64) {
        int nc = min(64, deg - c0);
        int s_l = 0;
        float4 e4 = make_float4(-INFINITY, -INFINITY, -INFINITY, -INFINITY);
        float emax_l = -INFINITY;
        if (lane < nc) {
            s_l = csr_src[start + c0 + lane];
            float4 el4 = *(const float4*)(el + (size_t)s_l * 4);
            e4.x = el4.x + er4.x; e4.x = e4.x > 0.f ? e4.x : 0.2f * e4.x;
            e4.y = el4.y + er4.y; e4.y = e4.y > 0.f ? e4.y : 0.2f * e4.y;
            e4.z = el4.z + er4.z; e4.z = e4.z > 0.f ? e4.z : 0.2f * e4.z;
            e4.w = el4.w + er4.w; e4.w = e4.w > 0.f ? e4.w : 0.2f * e4.w;
            emax_l = fmaxf(fmaxf(e4.x, e4.y), fmaxf(e4.z, e4.w));
        }
        float cm = emax_l;
#pragma unroll
        for (int off = 32; off; off >>= 1) cm = fmaxf(cm, __shfl_xor(cm, off));
        float newm = fmaxf(m, cm);
        float scale = __expf(m - newm);
        ssum.x *= scale; ssum.y *= scale; ssum.z *= scale; ssum.w *= scale;
        f32x2 sc2 = {scale, scale};
        acc01 *= sc2; acc23 *= sc2;
        m = newm;
        float4 p4 = make_float4(0.f, 0.f, 0.f, 0.f);
        if (lane < nc) {
            p4.x = __expf(e4.x - m);
            p4.y = __expf(e4.y - m);
            p4.z = __expf(e4.z - m);
            p4.w = __expf(e4.w - m);
        }
        float4 cs = p4;
#pragma unroll
        for (int off = 32; off; off >>= 1) {
            cs.x += __shfl_xor(cs.x, off);
            cs.y += __shfl_xor(cs.y, off);
            cs.z += __shfl_xor(cs.z, off);
            cs.w += __shfl_xor(cs.w, off);
        }
        ssum.x += cs.x; ssum.y += cs.y; ssum.z += cs.z; ssum.w += cs.w;
        *(float4*)&p_lds[wid][lane][0] = p4;
        s_lds[wid][lane] = s_l;

        for (int tt = 0; tt < nc; tt += 8) {
            float w[8]; unsigned off32[8];
#pragma unroll
            for (int j = 0; j < 8; ++j) {
                int idx = tt + j;
                int ic = idx < nc ? idx : 0;
                w[j] = idx < nc ? p_lds[wid][ic][hsel] : 0.f;
                off32[j] = ((unsigned)s_lds[wid][ic] << 9) + lb;
            }
            uint2 u[8];
#pragma unroll
            for (int j = 0; j < 8; ++j)
                u[j] = *(const uint2*)((const char*)zb + off32[j]);
#pragma unroll
            for (int j = 0; j < 8; ++j) {
                f32x2 v01, v23, ww = {w[j], w[j]};
                v01.x = __uint_as_float(u[j].x << 16);
                v01.y = __uint_as_float(u[j].x & 0xffff0000u);
                v23.x = __uint_as_float(u[j].y << 16);
                v23.y = __uint_as_float(u[j].y & 0xffff0000u);
                acc01 = __builtin_elementwise_fma(ww, v01, acc01);
                acc23 = __builtin_elementwise_fma(ww, v23, acc23);
            }
        }
    }
    float4 acc = make_float4(acc01.x, acc01.y, acc23.x, acc23.y);
    float s_h = hsel == 0 ? ssum.x : hsel == 1 ? ssum.y : hsel == 2 ? ssum.z : ssum.w;
    float inv = s_h > 0.f ? 1.f / s_h : 0.f;
    float4 b4 = *(const float4*)(bias + lane * 4);
    float ox = acc.x * inv + b4.x; ox = ox > 0.f ? ox : expm1f(ox);
    float oy = acc.y * inv + b4.y; oy = oy > 0.f ? oy : expm1f(oy);
    float oz = acc.z * inv + b4.z; oz = oz > 0.f ? oz : expm1f(oz);
    float ow = acc.w * inv + b4.w; ow = ow > 0.f ? ow : expm1f(ow);
    ushort4 o;
    o.x = f2bf(ox); o.y = f2bf(oy); o.z = f2bf(oz); o.w = f2bf(ow);
    *(ushort4*)(out + (size_t)n * 256 + lane * 4) = o;
}

// ---------------- layer-2 aggregate (H=1), r7 structure ----------------

__global__ void gat_aggregate_bf(const unsigned short* __restrict__ zb,  // [N,64] bf16
                                 const float* __restrict__ el, const float* __restrict__ er,
                                 const int* __restrict__ rowptr, const int* __restrict__ csr_src,
                                 const float* __restrict__ bias,
                                 float* __restrict__ out, int Nn)
{
    int gw = (blockIdx.x * blockDim.x + threadIdx.x) >> 6;
    int lane = threadIdx.x & 63;
    int n = gw;
    if (n >= Nn) return;
    int start = rowptr[n], end = rowptr[n + 1];
    int deg = end - start;
    float ern = er[n];

    int group = lane >> 4;
    int gl = lane & 15;
    const unsigned lb = (unsigned)(gl << 3);

    f32x2 acc01 = {0.f, 0.f}, acc23 = {0.f, 0.f};
    float m = -INFINITY;
    float ssum = 0.f;

    for (int c0 = 0; c0 < deg; c0 += 64) {
        int nc = min(64, deg - c0);
        int s_l = 0;
        float e_l = -INFINITY;
        if (lane < nc) {
            s_l = csr_src[start + c0 + lane];
            float e = el[s_l] + ern;
            e_l = e > 0.f ? e : 0.2f * e;
        }
        float cm = e_l;
#pragma unroll
        for (int off = 32; off; off >>= 1) cm = fmaxf(cm, __shfl_xor(cm, off));
        float newm = fmaxf(m, cm);
        float scale = __expf(m - newm);
        ssum *= scale;
        f32x2 sc2 = {scale, scale};
        acc01 *= sc2; acc23 *= sc2;
        m = newm;
        float p_l = (lane < nc) ? __expf(e_l - m) : 0.f;
        float cs = p_l;
#pragma unroll
        for (int off = 32; off; off >>= 1) cs += __shfl_xor(cs, off);
        ssum += cs;

        int nIter = (nc + 3) >> 2;
        for (int i0 = 0; i0 < nIter; i0 += 4) {
            float w[4]; unsigned off32[4];
#pragma unroll
            for (int j = 0; j < 4; ++j) {
                int tt = group + 4 * (i0 + j);
                int tc = tt & 63;
                float wv = __shfl(p_l, tc);
                int s = __shfl(s_l, tc);
                w[j] = (tt < nc) ? wv : 0.f;
                off32[j] = ((unsigned)s << 7) + lb;
            }
            uint2 u[4];
#pragma unroll
            for (int j = 0; j < 4; ++j)
                u[j] = *(const uint2*)((const char*)zb + off32[j]);
#pragma unroll
            for (int j = 0; j < 4; ++j) {
                f32x2 v01, v23, ww = {w[j], w[j]};
                v01.x = __uint_as_float(u[j].x << 16);
                v01.y = __uint_as_float(u[j].x & 0xffff0000u);
                v23.x = __uint_as_float(u[j].y << 16);
                v23.y = __uint_as_float(u[j].y & 0xffff0000u);
                acc01 = __builtin_elementwise_fma(ww, v01, acc01);
                acc23 = __builtin_elementwise_fma(ww, v23, acc23);
            }
        }
    }
    float4 acc = make_float4(acc01.x, acc01.y, acc23.x, acc23.y);
#pragma unroll
    for (int off = 16; off <= 32; off <<= 1) {
        acc.x += __shfl_xor(acc.x, off);
        acc.y += __shfl_xor(acc.y, off);
        acc.z += __shfl_xor(acc.z, off);
        acc.w += __shfl_xor(acc.w, off);
    }
    float inv = ssum > 0.f ? 1.f / ssum : 0.f;
    if (lane < 16) {
        float4 o;
        o.x = acc.x * inv + bias[gl * 4 + 0];
        o.y = acc.y * inv + bias[gl * 4 + 1];
        o.z = acc.z * inv + bias[gl * 4 + 2];
        o.w = acc.w * inv + bias[gl * 4 + 3];
        *(float4*)(out + (size_t)n * 64 + gl * 4) = o;
    }
}

// ---------------- launch ----------------

static inline size_t align_up(size_t x, size_t a) { return (x + a - 1) & ~(a - 1); }

extern "C" void kernel_launch(void* const* d_in, const int* in_sizes, int n_in,
                              void* d_out, int out_size, void* d_ws, size_t ws_size,
                              hipStream_t stream) {
    const float* x   = (const float*)d_in[0];
    const float* W1  = (const float*)d_in[1];
    const float* al1 = (const float*)d_in[2];
    const float* ar1 = (const float*)d_in[3];
    const float* b1  = (const float*)d_in[4];
    const float* W2  = (const float*)d_in[5];
    const float* al2 = (const float*)d_in[6];
    const float* ar2 = (const float*)d_in[7];
    const float* b2  = (const float*)d_in[8];
    const int*   src = (const int*)d_in[9];
    const int*   dst = (const int*)d_in[10];
    float* out = (float*)d_out;

    char* ws = (char*)d_ws;
    size_t off = 0;
    unsigned short* zb1 = (unsigned short*)(ws + off); off = align_up(off + (size_t)NN * 256 * 2, 256);
    unsigned short* h1b = (unsigned short*)(ws + off); off = align_up(off + (size_t)NN * 256 * 2, 256);
    unsigned short* zb2 = (unsigned short*)(ws + off); off = align_up(off + (size_t)NN * 64 * 2, 256);
    float* el1 = (float*)(ws + off); off = align_up(off + (size_t)NN * H1 * 4, 256);
    float* er1 = (float*)(ws + off); off = align_up(off + (size_t)NN * H1 * 4, 256);
    float* el2 = (float*)(ws + off); off = align_up(off + (size_t)NN * 4, 256);
    float* er2 = (float*)(ws + off); off = align_up(off + (size_t)NN * 4, 256);
    short* W1th = (short*)(ws + off); off = align_up(off + 256 * 256 * 2, 256);
    short* W1tl = (short*)(ws + off); off = align_up(off + 256 * 256 * 2, 256);
    short* W2th = (short*)(ws + off); off = align_up(off + 64 * 256 * 2, 256);
    short* W2tl = (short*)(ws + off); off = align_up(off + 64 * 256 * 2, 256);
    int* rowptr = (int*)(ws + off); off = align_up(off + (size_t)(NN + 1) * 4, 256);
    int* deg    = (int*)(ws + off); off = align_up(off + (size_t)NN * 4, 256);
    int* fillc  = (int*)(ws + off); off = align_up(off + (size_t)NN * 4, 256);
    int* csr_src = (int*)(ws + off); off = align_up(off + (size_t)EE * 4, 256);

    const int nEdgeBlocks = (EE + 255) / 256;
    const int nMBlocks128 = (NN + 127) / 128;  // 391

    hipMemsetAsync(deg, 0, (size_t)NN * 4, stream);
    hipMemsetAsync(fillc, 0, (size_t)NN * 4, stream);
    hist_wsplit<<<nEdgeBlocks, 256, 0, stream>>>(dst, deg, EE, W1, W2, W1th, W1tl, W2th, W2tl);
    scan_one<<<1, 1024, 0, stream>>>(deg, rowptr);
    fill_csr<<<nEdgeBlocks, 256, 0, stream>>>(src, dst, rowptr, fillc, csr_src, EE);

    // ---- layer 1: BM=128, BN=256 ----
    gemm_bf16x2<8, 1, 4, 256, 4, true><<<dim3(nMBlocks128, 1), 256, 0, stream>>>(
        x, W1th, W1tl, al1, ar1, zb1, el1, er1, NN, FIN);
    gat_aggregate_h4<<<(NN + 3) / 4, 256, 0, stream>>>(
        zb1, el1, er1, rowptr, csr_src, b1, h1b, NN);

    // ---- layer 2 ----
    gemm_bf16x2<2, 4, 1, 64, 1, false><<<dim3(nMBlocks128, 1), 256, 0, stream>>>(
        h1b, W2th, W2tl, al2, ar2, zb2, el2, er2, NN, H1 * HID);
    gat_aggregate_bf<<<(NN * 64 + 255) / 256, 256, 0, stream>>>(
        zb2, el2, er2, rowptr, csr_src, b2, out, NN);
}

// Round 10
// 292.535 us; speedup vs baseline: 1.0764x; 1.0764x over previous
//
#include <hip/hip_runtime.h>
#include <hip/hip_bf16.h>
#include <math.h>

#define NN 50000
#define EE 800000
#define FIN 256
#define HID 64
#define OUTD 64
#define H1 4
#define H2 1

typedef __attribute__((ext_vector_type(8))) short short8;
typedef __attribute__((ext_vector_type(4))) short short4v;
typedef __attribute__((ext_vector_type(4))) float f32x4;
typedef __attribute__((ext_vector_type(2))) float f32x2;

// ---------------- helpers ----------------

__device__ __forceinline__ unsigned short f2bf(float f) {   // round-to-nearest-even
    unsigned u = __float_as_uint(f);
    unsigned r = (u + 0x7FFFu + ((u >> 16) & 1u)) >> 16;
    return (unsigned short)r;
}
__device__ __forceinline__ float bf2f(unsigned short u) {
    return __uint_as_float(((unsigned)u) << 16);
}

// ---------------- CSR build ----------------
// hist + weight split fused (independent work, one launch)

__global__ void hist_wsplit(const int* __restrict__ dst, int* __restrict__ deg, int nE,
                            const float* __restrict__ W1, const float* __restrict__ W2,
                            short* __restrict__ W1th, short* __restrict__ W1tl,
                            short* __restrict__ W2th, short* __restrict__ W2tl) {
    int e = blockIdx.x * 256 + threadIdx.x;
    if (e < nE) atomicAdd(&deg[dst[e]], 1);
    int n = blockIdx.x;
    int k = threadIdx.x;
    if (n < 256) {
        float v = W1[(size_t)k * 256 + n];
        unsigned short hi = f2bf(v);
        unsigned short lo = f2bf(v - bf2f(hi));
        W1th[n * 256 + k] = (short)hi;
        W1tl[n * 256 + k] = (short)lo;
    } else if (n < 320) {
        int n2 = n - 256;
        float v = W2[(size_t)k * 64 + n2];
        unsigned short hi = f2bf(v);
        unsigned short lo = f2bf(v - bf2f(hi));
        W2th[n2 * 256 + k] = (short)hi;
        W2tl[n2 * 256 + k] = (short)lo;
    }
}

// single-block exclusive scan of deg[0..NN) -> rowptr, rowptr[NN]=EE
#define SCAN_CH 49
__global__ __launch_bounds__(1024) void scan_one(const int* __restrict__ deg,
                                                 int* __restrict__ rowptr) {
    __shared__ int wsum[16];
    int tid = threadIdx.x;
    int lane = tid & 63;
    int base = tid * SCAN_CH;
    int loc[SCAN_CH];
    int tot = 0;
#pragma unroll
    for (int j = 0; j < SCAN_CH; ++j) {
        int idx = base + j;
        int v = (idx < NN) ? deg[idx] : 0;
        loc[j] = tot;            // exclusive within chunk
        tot += v;
    }
    int incl = tot;
#pragma unroll
    for (int off = 1; off < 64; off <<= 1) {
        int t = __shfl_up(incl, off);
        if (lane >= off) incl += t;
    }
    if (lane == 63) wsum[tid >> 6] = incl;
    __syncthreads();
    if (tid == 0) {
        int run = 0;
#pragma unroll
        for (int i = 0; i < 16; ++i) { int t = wsum[i]; wsum[i] = run; run += t; }
    }
    __syncthreads();
    int excl = wsum[tid >> 6] + incl - tot;
#pragma unroll
    for (int j = 0; j < SCAN_CH; ++j) {
        int idx = base + j;
        if (idx < NN) rowptr[idx] = excl + loc[j];
    }
    if (tid == 0) rowptr[NN] = EE;
}

__global__ void fill_csr(const int* __restrict__ src, const int* __restrict__ dst,
                         const int* __restrict__ rowptr, int* __restrict__ fillc,
                         int* __restrict__ csr_src, int nE) {
    int e = blockIdx.x * 256 + threadIdx.x;
    if (e < nE) {
        int d = dst[e];
        int pos = rowptr[d] + atomicAdd(&fillc[d], 1);
        csr_src[pos] = src[e];
    }
}

// ---------------- MFMA GEMM + fused scores epilogue ----------
// ASPLIT=true : A f32, split to hi/lo in staging, 3 MFMA passes.
// ASPLIT=false: A already bf16 (exact), 2 MFMA passes.
// NOTE (r9 lesson): keep LDS <= ~51KB so >=3 blocks/CU; BM=128/BN=256 (60KB)
// dropped to 1 block/CU and ran 3x slower.

template<int MF, int WR, int WC, int NT, int H, bool ASPLIT>
__global__ __launch_bounds__(256) void gemm_bf16x2(
    const void* __restrict__ Av, const short* __restrict__ Bth, const short* __restrict__ Btl,
    const float* __restrict__ al, const float* __restrict__ ar,
    unsigned short* __restrict__ zb, float* __restrict__ el, float* __restrict__ er,
    int M, int K)
{
    constexpr int BM = WR * MF * 16;
    constexpr int BN = WC * 64;
    __shared__ short Ah[BM * 40];
    __shared__ short Al[ASPLIT ? BM * 40 : 8];
    __shared__ short Bh[BN * 40], Bl[BN * 40];

    const int bm = blockIdx.x * BM;
    const int bn = blockIdx.y * BN;
    const int t = threadIdx.x;
    const int wid = t >> 6;
    const int lane = t & 63;
    const int lr = lane & 15;
    const int lg = lane >> 4;
    const int wr = wid / WC;
    const int wc = wid % WC;

    f32x4 acc[MF][4];
#pragma unroll
    for (int mf = 0; mf < MF; ++mf)
#pragma unroll
        for (int nf = 0; nf < 4; ++nf) acc[mf][nf] = (f32x4)(0.f);

    for (int k0 = 0; k0 < K; k0 += 32) {
        if constexpr (ASPLIT) {
            const float* A = (const float*)Av;
#pragma unroll
            for (int q = 0; q < BM / 32; ++q) {
                int linear = q * 256 + t;
                int row = linear >> 3;
                int kq = (linear & 7) * 4;
                int grow = bm + row;
                float4 av = make_float4(0.f, 0.f, 0.f, 0.f);
                if (grow < M) av = *(const float4*)(A + (size_t)grow * K + k0 + kq);
                short4v hi, lo;
                unsigned short h0 = f2bf(av.x); hi.x = (short)h0; lo.x = (short)f2bf(av.x - bf2f(h0));
                unsigned short h1v = f2bf(av.y); hi.y = (short)h1v; lo.y = (short)f2bf(av.y - bf2f(h1v));
                unsigned short h2v = f2bf(av.z); hi.z = (short)h2v; lo.z = (short)f2bf(av.z - bf2f(h2v));
                unsigned short h3v = f2bf(av.w); hi.w = (short)h3v; lo.w = (short)f2bf(av.w - bf2f(h3v));
                *(short4v*)&Ah[row * 40 + kq] = hi;
                *(short4v*)&Al[row * 40 + kq] = lo;
            }
        } else {
            const unsigned short* A = (const unsigned short*)Av;
#pragma unroll
            for (int q = 0; q < BM / 64; ++q) {
                int linear = q * 256 + t;
                int row = linear >> 2;
                int k8 = (linear & 3) * 8;
                int grow = bm + row;
                short8 v = (short8)(0);
                if (grow < M) v = *(const short8*)(A + (size_t)grow * K + k0 + k8);
                *(short8*)&Ah[row * 40 + k8] = v;
            }
        }
#pragma unroll
        for (int q = 0; q < BN / 64; ++q) {
            int linear = q * 256 + t;
            int n = linear >> 2;
            int k8 = (linear & 3) * 8;
            short8 vh = *(const short8*)(Bth + (size_t)(bn + n) * K + k0 + k8);
            short8 vl = *(const short8*)(Btl + (size_t)(bn + n) * K + k0 + k8);
            *(short8*)&Bh[n * 40 + k8] = vh;
            *(short8*)&Bl[n * 40 + k8] = vl;
        }
        __syncthreads();

        short8 bh[4], blo[4];
#pragma unroll
        for (int nf = 0; nf < 4; ++nf) {
            int col = wc * 64 + nf * 16 + lr;
            bh[nf]  = *(const short8*)&Bh[col * 40 + lg * 8];
            blo[nf] = *(const short8*)&Bl[col * 40 + lg * 8];
        }
#pragma unroll
        for (int mf = 0; mf < MF; ++mf) {
            int row = wr * MF * 16 + mf * 16 + lr;
            short8 ah = *(const short8*)&Ah[row * 40 + lg * 8];
            short8 alo;
            if constexpr (ASPLIT) alo = *(const short8*)&Al[row * 40 + lg * 8];
#pragma unroll
            for (int nf = 0; nf < 4; ++nf) {
                acc[mf][nf] = __builtin_amdgcn_mfma_f32_16x16x32_bf16(ah, bh[nf],  acc[mf][nf], 0, 0, 0);
                acc[mf][nf] = __builtin_amdgcn_mfma_f32_16x16x32_bf16(ah, blo[nf], acc[mf][nf], 0, 0, 0);
                if constexpr (ASPLIT)
                    acc[mf][nf] = __builtin_amdgcn_mfma_f32_16x16x32_bf16(alo, bh[nf], acc[mf][nf], 0, 0, 0);
            }
        }
        __syncthreads();
    }

    // ---- epilogue: zb (bf16) + el/er ----
    const int h = (bn + wc * 64) >> 6;
    float alv[4], arv[4];
#pragma unroll
    for (int nf = 0; nf < 4; ++nf) {
        alv[nf] = al[h * 64 + nf * 16 + lr];
        arv[nf] = ar[h * 64 + nf * 16 + lr];
    }
#pragma unroll
    for (int mf = 0; mf < MF; ++mf) {
#pragma unroll
        for (int j = 0; j < 4; ++j) {
            int row = bm + wr * MF * 16 + mf * 16 + lg * 4 + j;
            float sel = 0.f, ser = 0.f;
#pragma unroll
            for (int nf = 0; nf < 4; ++nf) {
                float v = acc[mf][nf][j];
                sel += v * alv[nf];
                ser += v * arv[nf];
                if (row < M)
                    zb[(size_t)row * NT + bn + wc * 64 + nf * 16 + lr] = f2bf(v);
            }
#pragma unroll
            for (int off = 1; off <= 8; off <<= 1) {
                sel += __shfl_xor(sel, off);
                ser += __shfl_xor(ser, off);
            }
            if (lr == 0 && row < M) {
                el[(size_t)row * H + h] = sel;
                er[(size_t)row * H + h] = ser;
            }
        }
    }
}

// ---------------- layer-1 aggregate (r7 structure: best measured) ----------------
// One wave per node, 4 heads merged; lane owns 8B (4 channels, head lane>>4);
// batches of 8 edges: 8 offsets+weights, 8 loads in flight, packed FMAs.

__global__ __launch_bounds__(256) void gat_aggregate_h4(
    const unsigned short* __restrict__ zb,   // [N,256] bf16
    const float* __restrict__ el,            // [N,4]
    const float* __restrict__ er,            // [N,4]
    const int* __restrict__ rowptr, const int* __restrict__ csr_src,
    const float* __restrict__ bias,          // [256]
    unsigned short* __restrict__ out,        // [N,256] bf16 (ELU applied)
    int Nn)
{
    __shared__ float p_lds[4][64][4];
    __shared__ int   s_lds[4][64];
    int wid = threadIdx.x >> 6;
    int lane = threadIdx.x & 63;
    int n = blockIdx.x * 4 + wid;
    if (n >= Nn) return;
    int start = rowptr[n], end = rowptr[n + 1];
    int deg = end - start;
    float4 er4 = *(const float4*)(er + (size_t)n * 4);
    int hsel = lane >> 4;
    const unsigned lb = (unsigned)(lane << 3);   // byte offset of this lane in a 512B row

    f32x2 acc01 = {0.f, 0.f}, acc23 = {0.f, 0.f};
    float4 ssum = make_float4(0.f, 0.f, 0.f, 0.f);
    float m = -INFINITY;

    for (int c0 = 0; c0 < deg; c0 += 64) {
        int nc = min(64, deg - c0);
        int s_l = 0;
        float4 e4 = make_float4(-INFINITY, -INFINITY, -INFINITY, -INFINITY);
        float emax_l = -INFINITY;
        if (lane < nc) {
            s_l = csr_src[start + c0 + lane];
            float4 el4 = *(const float4*)(el + (size_t)s_l * 4);
            e4.x = el4.x + er4.x; e4.x = e4.x > 0.f ? e4.x : 0.2f * e4.x;
            e4.y = el4.y + er4.y; e4.y = e4.y > 0.f ? e4.y : 0.2f * e4.y;
            e4.z = el4.z + er4.z; e4.z = e4.z > 0.f ? e4.z : 0.2f * e4.z;
            e4.w = el4.w + er4.w; e4.w = e4.w > 0.f ? e4.w : 0.2f * e4.w;
            emax_l = fmaxf(fmaxf(e4.x, e4.y), fmaxf(e4.z, e4.w));
        }
        float cm = emax_l;
#pragma unroll
        for (int off = 32; off; off >>= 1) cm = fmaxf(cm, __shfl_xor(cm, off));
        float newm = fmaxf(m, cm);
        float scale = __expf(m - newm);
        ssum.x *= scale; ssum.y *= scale; ssum.z *= scale; ssum.w *= scale;
        f32x2 sc2 = {scale, scale};
        acc01 *= sc2; acc23 *= sc2;
        m = newm;
        float4 p4 = make_float4(0.f, 0.f, 0.f, 0.f);
        if (lane < nc) {
            p4.x = __expf(e4.x - m);
            p4.y = __expf(e4.y - m);
            p4.z = __expf(e4.z - m);
            p4.w = __expf(e4.w - m);
        }
        float4 cs = p4;
#pragma unroll
        for (int off = 32; off; off >>= 1) {
            cs.x += __shfl_xor(cs.x, off);
            cs.y += __shfl_xor(cs.y, off);
            cs.z += __shfl_xor(cs.z, off);
            cs.w += __shfl_xor(cs.w, off);
        }
        ssum.x += cs.x; ssum.y += cs.y; ssum.z += cs.z; ssum.w += cs.w;
        *(float4*)&p_lds[wid][lane][0] = p4;
        s_lds[wid][lane] = s_l;

        for (int tt = 0; tt < nc; tt += 8) {
            float w[8]; unsigned off32[8];
#pragma unroll
            for (int j = 0; j < 8; ++j) {
                int idx = tt + j;
                int ic = idx < nc ? idx : 0;
                w[j] = idx < nc ? p_lds[wid][ic][hsel] : 0.f;
                off32[j] = ((unsigned)s_lds[wid][ic] << 9) + lb;
            }
            uint2 u[8];
#pragma unroll
            for (int j = 0; j < 8; ++j)
                u[j] = *(const uint2*)((const char*)zb + off32[j]);
#pragma unroll
            for (int j = 0; j < 8; ++j) {
                f32x2 v01, v23, ww = {w[j], w[j]};
                v01.x = __uint_as_float(u[j].x << 16);
                v01.y = __uint_as_float(u[j].x & 0xffff0000u);
                v23.x = __uint_as_float(u[j].y << 16);
                v23.y = __uint_as_float(u[j].y & 0xffff0000u);
                acc01 = __builtin_elementwise_fma(ww, v01, acc01);
                acc23 = __builtin_elementwise_fma(ww, v23, acc23);
            }
        }
    }
    float4 acc = make_float4(acc01.x, acc01.y, acc23.x, acc23.y);
    float s_h = hsel == 0 ? ssum.x : hsel == 1 ? ssum.y : hsel == 2 ? ssum.z : ssum.w;
    float inv = s_h > 0.f ? 1.f / s_h : 0.f;
    float4 b4 = *(const float4*)(bias + lane * 4);
    float ox = acc.x * inv + b4.x; ox = ox > 0.f ? ox : expm1f(ox);
    float oy = acc.y * inv + b4.y; oy = oy > 0.f ? oy : expm1f(oy);
    float oz = acc.z * inv + b4.z; oz = oz > 0.f ? oz : expm1f(oz);
    float ow = acc.w * inv + b4.w; ow = ow > 0.f ? ow : expm1f(ow);
    ushort4 o;
    o.x = f2bf(ox); o.y = f2bf(oy); o.z = f2bf(oz); o.w = f2bf(ow);
    *(ushort4*)(out + (size_t)n * 256 + lane * 4) = o;
}

// ---------------- layer-2 aggregate (H=1), r7 structure ----------------

__global__ void gat_aggregate_bf(const unsigned short* __restrict__ zb,  // [N,64] bf16
                                 const float* __restrict__ el, const float* __restrict__ er,
                                 const int* __restrict__ rowptr, const int* __restrict__ csr_src,
                                 const float* __restrict__ bias,
                                 float* __restrict__ out, int Nn)
{
    int gw = (blockIdx.x * blockDim.x + threadIdx.x) >> 6;
    int lane = threadIdx.x & 63;
    int n = gw;
    if (n >= Nn) return;
    int start = rowptr[n], end = rowptr[n + 1];
    int deg = end - start;
    float ern = er[n];

    int group = lane >> 4;
    int gl = lane & 15;
    const unsigned lb = (unsigned)(gl << 3);

    f32x2 acc01 = {0.f, 0.f}, acc23 = {0.f, 0.f};
    float m = -INFINITY;
    float ssum = 0.f;

    for (int c0 = 0; c0 < deg; c0 += 64) {
        int nc = min(64, deg - c0);
        int s_l = 0;
        float e_l = -INFINITY;
        if (lane < nc) {
            s_l = csr_src[start + c0 + lane];
            float e = el[s_l] + ern;
            e_l = e > 0.f ? e : 0.2f * e;
        }
        float cm = e_l;
#pragma unroll
        for (int off = 32; off; off >>= 1) cm = fmaxf(cm, __shfl_xor(cm, off));
        float newm = fmaxf(m, cm);
        float scale = __expf(m - newm);
        ssum *= scale;
        f32x2 sc2 = {scale, scale};
        acc01 *= sc2; acc23 *= sc2;
        m = newm;
        float p_l = (lane < nc) ? __expf(e_l - m) : 0.f;
        float cs = p_l;
#pragma unroll
        for (int off = 32; off; off >>= 1) cs += __shfl_xor(cs, off);
        ssum += cs;

        int nIter = (nc + 3) >> 2;
        for (int i0 = 0; i0 < nIter; i0 += 4) {
            float w[4]; unsigned off32[4];
#pragma unroll
            for (int j = 0; j < 4; ++j) {
                int tt = group + 4 * (i0 + j);
                int tc = tt & 63;
                float wv = __shfl(p_l, tc);
                int s = __shfl(s_l, tc);
                w[j] = (tt < nc) ? wv : 0.f;
                off32[j] = ((unsigned)s << 7) + lb;
            }
            uint2 u[4];
#pragma unroll
            for (int j = 0; j < 4; ++j)
                u[j] = *(const uint2*)((const char*)zb + off32[j]);
#pragma unroll
            for (int j = 0; j < 4; ++j) {
                f32x2 v01, v23, ww = {w[j], w[j]};
                v01.x = __uint_as_float(u[j].x << 16);
                v01.y = __uint_as_float(u[j].x & 0xffff0000u);
                v23.x = __uint_as_float(u[j].y << 16);
                v23.y = __uint_as_float(u[j].y & 0xffff0000u);
                acc01 = __builtin_elementwise_fma(ww, v01, acc01);
                acc23 = __builtin_elementwise_fma(ww, v23, acc23);
            }
        }
    }
    float4 acc = make_float4(acc01.x, acc01.y, acc23.x, acc23.y);
#pragma unroll
    for (int off = 16; off <= 32; off <<= 1) {
        acc.x += __shfl_xor(acc.x, off);
        acc.y += __shfl_xor(acc.y, off);
        acc.z += __shfl_xor(acc.z, off);
        acc.w += __shfl_xor(acc.w, off);
    }
    float inv = ssum > 0.f ? 1.f / ssum : 0.f;
    if (lane < 16) {
        float4 o;
        o.x = acc.x * inv + bias[gl * 4 + 0];
        o.y = acc.y * inv + bias[gl * 4 + 1];
        o.z = acc.z * inv + bias[gl * 4 + 2];
        o.w = acc.w * inv + bias[gl * 4 + 3];
        *(float4*)(out + (size_t)n * 64 + gl * 4) = o;
    }
}

// ---------------- launch ----------------

static inline size_t align_up(size_t x, size_t a) { return (x + a - 1) & ~(a - 1); }

extern "C" void kernel_launch(void* const* d_in, const int* in_sizes, int n_in,
                              void* d_out, int out_size, void* d_ws, size_t ws_size,
                              hipStream_t stream) {
    const float* x   = (const float*)d_in[0];
    const float* W1  = (const float*)d_in[1];
    const float* al1 = (const float*)d_in[2];
    const float* ar1 = (const float*)d_in[3];
    const float* b1  = (const float*)d_in[4];
    const float* W2  = (const float*)d_in[5];
    const float* al2 = (const float*)d_in[6];
    const float* ar2 = (const float*)d_in[7];
    const float* b2  = (const float*)d_in[8];
    const int*   src = (const int*)d_in[9];
    const int*   dst = (const int*)d_in[10];
    float* out = (float*)d_out;

    char* ws = (char*)d_ws;
    size_t off = 0;
    unsigned short* zb1 = (unsigned short*)(ws + off); off = align_up(off + (size_t)NN * 256 * 2, 256);
    unsigned short* h1b = (unsigned short*)(ws + off); off = align_up(off + (size_t)NN * 256 * 2, 256);
    unsigned short* zb2 = (unsigned short*)(ws + off); off = align_up(off + (size_t)NN * 64 * 2, 256);
    float* el1 = (float*)(ws + off); off = align_up(off + (size_t)NN * H1 * 4, 256);
    float* er1 = (float*)(ws + off); off = align_up(off + (size_t)NN * H1 * 4, 256);
    float* el2 = (float*)(ws + off); off = align_up(off + (size_t)NN * 4, 256);
    float* er2 = (float*)(ws + off); off = align_up(off + (size_t)NN * 4, 256);
    short* W1th = (short*)(ws + off); off = align_up(off + 256 * 256 * 2, 256);
    short* W1tl = (short*)(ws + off); off = align_up(off + 256 * 256 * 2, 256);
    short* W2th = (short*)(ws + off); off = align_up(off + 64 * 256 * 2, 256);
    short* W2tl = (short*)(ws + off); off = align_up(off + 64 * 256 * 2, 256);
    int* rowptr = (int*)(ws + off); off = align_up(off + (size_t)(NN + 1) * 4, 256);
    int* deg    = (int*)(ws + off); off = align_up(off + (size_t)NN * 4, 256);
    int* fillc  = (int*)(ws + off); off = align_up(off + (size_t)NN * 4, 256);
    int* csr_src = (int*)(ws + off); off = align_up(off + (size_t)EE * 4, 256);

    const int nEdgeBlocks = (EE + 255) / 256;
    const int nMBlocks64 = (NN + 63) / 64;     // 782
    const int nMBlocks128 = (NN + 127) / 128;  // 391

    hipMemsetAsync(deg, 0, (size_t)NN * 4, stream);
    hipMemsetAsync(fillc, 0, (size_t)NN * 4, stream);
    hist_wsplit<<<nEdgeBlocks, 256, 0, stream>>>(dst, deg, EE, W1, W2, W1th, W1tl, W2th, W2tl);
    scan_one<<<1, 1024, 0, stream>>>(deg, rowptr);
    fill_csr<<<nEdgeBlocks, 256, 0, stream>>>(src, dst, rowptr, fillc, csr_src, EE);

    // ---- layer 1: BM=64, BN=256, 3 blocks/CU ----
    gemm_bf16x2<4, 1, 4, 256, 4, true><<<dim3(nMBlocks64, 1), 256, 0, stream>>>(
        x, W1th, W1tl, al1, ar1, zb1, el1, er1, NN, FIN);
    gat_aggregate_h4<<<(NN + 3) / 4, 256, 0, stream>>>(
        zb1, el1, er1, rowptr, csr_src, b1, h1b, NN);

    // ---- layer 2 ----
    gemm_bf16x2<2, 4, 1, 64, 1, false><<<dim3(nMBlocks128, 1), 256, 0, stream>>>(
        h1b, W2th, W2tl, al2, ar2, zb2, el2, er2, NN, H1 * HID);
    gat_aggregate_bf<<<(NN * 64 + 255) / 256, 256, 0, stream>>>(
        zb2, el2, er2, rowptr, csr_src, b2, out, NN);
}

// Round 11
// 292.401 us; speedup vs baseline: 1.0769x; 1.0005x over previous
//
#include <hip/hip_runtime.h>
#include <hip/hip_bf16.h>
#include <math.h>

#define NN 50000
#define EE 800000
#define FIN 256
#define HID 64
#define OUTD 64
#define H1 4
#define H2 1

typedef __attribute__((ext_vector_type(8))) short short8;
typedef __attribute__((ext_vector_type(4))) short short4v;
typedef __attribute__((ext_vector_type(4))) float f32x4;
typedef __attribute__((ext_vector_type(2))) float f32x2;

// ---------------- helpers ----------------

__device__ __forceinline__ unsigned short f2bf(float f) {   // round-to-nearest-even
    unsigned u = __float_as_uint(f);
    unsigned r = (u + 0x7FFFu + ((u >> 16) & 1u)) >> 16;
    return (unsigned short)r;
}
__device__ __forceinline__ float bf2f(unsigned short u) {
    return __uint_as_float(((unsigned)u) << 16);
}

// ---------------- CSR build ----------------
// hist + weight split fused (independent work, one launch)

__global__ void hist_wsplit(const int* __restrict__ dst, int* __restrict__ deg, int nE,
                            const float* __restrict__ W1, const float* __restrict__ W2,
                            short* __restrict__ W1th, short* __restrict__ W1tl,
                            short* __restrict__ W2th, short* __restrict__ W2tl) {
    int e = blockIdx.x * 256 + threadIdx.x;
    if (e < nE) atomicAdd(&deg[dst[e]], 1);
    int n = blockIdx.x;
    int k = threadIdx.x;
    if (n < 256) {
        float v = W1[(size_t)k * 256 + n];
        unsigned short hi = f2bf(v);
        unsigned short lo = f2bf(v - bf2f(hi));
        W1th[n * 256 + k] = (short)hi;
        W1tl[n * 256 + k] = (short)lo;
    } else if (n < 320) {
        int n2 = n - 256;
        float v = W2[(size_t)k * 64 + n2];
        unsigned short hi = f2bf(v);
        unsigned short lo = f2bf(v - bf2f(hi));
        W2th[n2 * 256 + k] = (short)hi;
        W2tl[n2 * 256 + k] = (short)lo;
    }
}

// single-block exclusive scan of deg[0..NN) -> rowptr, rowptr[NN]=EE
#define SCAN_CH 49
__global__ __launch_bounds__(1024) void scan_one(const int* __restrict__ deg,
                                                 int* __restrict__ rowptr) {
    __shared__ int wsum[16];
    int tid = threadIdx.x;
    int lane = tid & 63;
    int base = tid * SCAN_CH;
    int loc[SCAN_CH];
    int tot = 0;
#pragma unroll
    for (int j = 0; j < SCAN_CH; ++j) {
        int idx = base + j;
        int v = (idx < NN) ? deg[idx] : 0;
        loc[j] = tot;            // exclusive within chunk
        tot += v;
    }
    int incl = tot;
#pragma unroll
    for (int off = 1; off < 64; off <<= 1) {
        int t = __shfl_up(incl, off);
        if (lane >= off) incl += t;
    }
    if (lane == 63) wsum[tid >> 6] = incl;
    __syncthreads();
    if (tid == 0) {
        int run = 0;
#pragma unroll
        for (int i = 0; i < 16; ++i) { int t = wsum[i]; wsum[i] = run; run += t; }
    }
    __syncthreads();
    int excl = wsum[tid >> 6] + incl - tot;
#pragma unroll
    for (int j = 0; j < SCAN_CH; ++j) {
        int idx = base + j;
        if (idx < NN) rowptr[idx] = excl + loc[j];
    }
    if (tid == 0) rowptr[NN] = EE;
}

__global__ void fill_csr(const int* __restrict__ src, const int* __restrict__ dst,
                         const int* __restrict__ rowptr, int* __restrict__ fillc,
                         int* __restrict__ csr_src, int nE) {
    int e = blockIdx.x * 256 + threadIdx.x;
    if (e < nE) {
        int d = dst[e];
        int pos = rowptr[d] + atomicAdd(&fillc[d], 1);
        csr_src[pos] = src[e];
    }
}

// ---------------- MFMA GEMM + fused scores epilogue ----------
// ASPLIT=true : A f32, split to hi/lo in staging, 3 MFMA passes.
// ASPLIT=false: A already bf16 (exact), 2 MFMA passes.
// NOTE (r9 lesson): keep LDS <= ~51KB so >=3 blocks/CU; BM=128/BN=256 (60KB)
// dropped to 1 block/CU and ran 3x slower.

template<int MF, int WR, int WC, int NT, int H, bool ASPLIT>
__global__ __launch_bounds__(256) void gemm_bf16x2(
    const void* __restrict__ Av, const short* __restrict__ Bth, const short* __restrict__ Btl,
    const float* __restrict__ al, const float* __restrict__ ar,
    unsigned short* __restrict__ zb, float* __restrict__ el, float* __restrict__ er,
    int M, int K)
{
    constexpr int BM = WR * MF * 16;
    constexpr int BN = WC * 64;
    __shared__ short Ah[BM * 40];
    __shared__ short Al[ASPLIT ? BM * 40 : 8];
    __shared__ short Bh[BN * 40], Bl[BN * 40];

    const int bm = blockIdx.x * BM;
    const int bn = blockIdx.y * BN;
    const int t = threadIdx.x;
    const int wid = t >> 6;
    const int lane = t & 63;
    const int lr = lane & 15;
    const int lg = lane >> 4;
    const int wr = wid / WC;
    const int wc = wid % WC;

    f32x4 acc[MF][4];
#pragma unroll
    for (int mf = 0; mf < MF; ++mf)
#pragma unroll
        for (int nf = 0; nf < 4; ++nf) acc[mf][nf] = (f32x4)(0.f);

    for (int k0 = 0; k0 < K; k0 += 32) {
        if constexpr (ASPLIT) {
            const float* A = (const float*)Av;
#pragma unroll
            for (int q = 0; q < BM / 32; ++q) {
                int linear = q * 256 + t;
                int row = linear >> 3;
                int kq = (linear & 7) * 4;
                int grow = bm + row;
                float4 av = make_float4(0.f, 0.f, 0.f, 0.f);
                if (grow < M) av = *(const float4*)(A + (size_t)grow * K + k0 + kq);
                short4v hi, lo;
                unsigned short h0 = f2bf(av.x); hi.x = (short)h0; lo.x = (short)f2bf(av.x - bf2f(h0));
                unsigned short h1v = f2bf(av.y); hi.y = (short)h1v; lo.y = (short)f2bf(av.y - bf2f(h1v));
                unsigned short h2v = f2bf(av.z); hi.z = (short)h2v; lo.z = (short)f2bf(av.z - bf2f(h2v));
                unsigned short h3v = f2bf(av.w); hi.w = (short)h3v; lo.w = (short)f2bf(av.w - bf2f(h3v));
                *(short4v*)&Ah[row * 40 + kq] = hi;
                *(short4v*)&Al[row * 40 + kq] = lo;
            }
        } else {
            const unsigned short* A = (const unsigned short*)Av;
#pragma unroll
            for (int q = 0; q < BM / 64; ++q) {
                int linear = q * 256 + t;
                int row = linear >> 2;
                int k8 = (linear & 3) * 8;
                int grow = bm + row;
                short8 v = (short8)(0);
                if (grow < M) v = *(const short8*)(A + (size_t)grow * K + k0 + k8);
                *(short8*)&Ah[row * 40 + k8] = v;
            }
        }
#pragma unroll
        for (int q = 0; q < BN / 64; ++q) {
            int linear = q * 256 + t;
            int n = linear >> 2;
            int k8 = (linear & 3) * 8;
            short8 vh = *(const short8*)(Bth + (size_t)(bn + n) * K + k0 + k8);
            short8 vl = *(const short8*)(Btl + (size_t)(bn + n) * K + k0 + k8);
            *(short8*)&Bh[n * 40 + k8] = vh;
            *(short8*)&Bl[n * 40 + k8] = vl;
        }
        __syncthreads();

        short8 bh[4], blo[4];
#pragma unroll
        for (int nf = 0; nf < 4; ++nf) {
            int col = wc * 64 + nf * 16 + lr;
            bh[nf]  = *(const short8*)&Bh[col * 40 + lg * 8];
            blo[nf] = *(const short8*)&Bl[col * 40 + lg * 8];
        }
#pragma unroll
        for (int mf = 0; mf < MF; ++mf) {
            int row = wr * MF * 16 + mf * 16 + lr;
            short8 ah = *(const short8*)&Ah[row * 40 + lg * 8];
            short8 alo;
            if constexpr (ASPLIT) alo = *(const short8*)&Al[row * 40 + lg * 8];
#pragma unroll
            for (int nf = 0; nf < 4; ++nf) {
                acc[mf][nf] = __builtin_amdgcn_mfma_f32_16x16x32_bf16(ah, bh[nf],  acc[mf][nf], 0, 0, 0);
                acc[mf][nf] = __builtin_amdgcn_mfma_f32_16x16x32_bf16(ah, blo[nf], acc[mf][nf], 0, 0, 0);
                if constexpr (ASPLIT)
                    acc[mf][nf] = __builtin_amdgcn_mfma_f32_16x16x32_bf16(alo, bh[nf], acc[mf][nf], 0, 0, 0);
            }
        }
        __syncthreads();
    }

    // ---- epilogue: zb (bf16) + el/er ----
    const int h = (bn + wc * 64) >> 6;
    float alv[4], arv[4];
#pragma unroll
    for (int nf = 0; nf < 4; ++nf) {
        alv[nf] = al[h * 64 + nf * 16 + lr];
        arv[nf] = ar[h * 64 + nf * 16 + lr];
    }
#pragma unroll
    for (int mf = 0; mf < MF; ++mf) {
#pragma unroll
        for (int j = 0; j < 4; ++j) {
            int row = bm + wr * MF * 16 + mf * 16 + lg * 4 + j;
            float sel = 0.f, ser = 0.f;
#pragma unroll
            for (int nf = 0; nf < 4; ++nf) {
                float v = acc[mf][nf][j];
                sel += v * alv[nf];
                ser += v * arv[nf];
                if (row < M)
                    zb[(size_t)row * NT + bn + wc * 64 + nf * 16 + lr] = f2bf(v);
            }
#pragma unroll
            for (int off = 1; off <= 8; off <<= 1) {
                sel += __shfl_xor(sel, off);
                ser += __shfl_xor(ser, off);
            }
            if (lr == 0 && row < M) {
                el[(size_t)row * H + h] = sel;
                er[(size_t)row * H + h] = ser;
            }
        }
    }
}

// ---------------- layer-1 aggregate (r7 structure: best measured) ----------------
// One wave per node, 4 heads merged; lane owns 8B (4 channels, head lane>>4);
// batches of 8 edges: 8 offsets+weights, 8 loads in flight, packed FMAs.

__global__ __launch_bounds__(256) void gat_aggregate_h4(
    const unsigned short* __restrict__ zb,   // [N,256] bf16
    const float* __restrict__ el,            // [N,4]
    const float* __restrict__ er,            // [N,4]
    const int* __restrict__ rowptr, const int* __restrict__ csr_src,
    const float* __restrict__ bias,          // [256]
    unsigned short* __restrict__ out,        // [N,256] bf16 (ELU applied)
    int Nn)
{
    __shared__ float p_lds[4][64][4];
    __shared__ int   s_lds[4][64];
    int wid = threadIdx.x >> 6;
    int lane = threadIdx.x & 63;
    int n = blockIdx.x * 4 + wid;
    if (n >= Nn) return;
    int start = rowptr[n], end = rowptr[n + 1];
    int deg = end - start;
    float4 er4 = *(const float4*)(er + (size_t)n * 4);
    int hsel = lane >> 4;
    const unsigned lb = (unsigned)(lane << 3);   // byte offset of this lane in a 512B row

    f32x2 acc01 = {0.f, 0.f}, acc23 = {0.f, 0.f};
    float4 ssum = make_float4(0.f, 0.f, 0.f, 0.f);
    float m = -INFINITY;

    for (int c0 = 0; c0 < deg; c0 += 64) {
        int nc = min(64, deg - c0);
        int s_l = 0;
        float4 e4 = make_float4(-INFINITY, -INFINITY, -INFINITY, -INFINITY);
        float emax_l = -INFINITY;
        if (lane < nc) {
            s_l = csr_src[start + c0 + lane];
            float4 el4 = *(const float4*)(el + (size_t)s_l * 4);
            e4.x = el4.x + er4.x; e4.x = e4.x > 0.f ? e4.x : 0.2f * e4.x;
            e4.y = el4.y + er4.y; e4.y = e4.y > 0.f ? e4.y : 0.2f * e4.y;
            e4.z = el4.z + er4.z; e4.z = e4.z > 0.f ? e4.z : 0.2f * e4.z;
            e4.w = el4.w + er4.w; e4.w = e4.w > 0.f ? e4.w : 0.2f * e4.w;
            emax_l = fmaxf(fmaxf(e4.x, e4.y), fmaxf(e4.z, e4.w));
        }
        float cm = emax_l;
#pragma unroll
        for (int off = 32; off; off >>= 1) cm = fmaxf(cm, __shfl_xor(cm, off));
        float newm = fmaxf(m, cm);
        float scale = __expf(m - newm);
        ssum.x *= scale; ssum.y *= scale; ssum.z *= scale; ssum.w *= scale;
        f32x2 sc2 = {scale, scale};
        acc01 *= sc2; acc23 *= sc2;
        m = newm;
        float4 p4 = make_float4(0.f, 0.f, 0.f, 0.f);
        if (lane < nc) {
            p4.x = __expf(e4.x - m);
            p4.y = __expf(e4.y - m);
            p4.z = __expf(e4.z - m);
            p4.w = __expf(e4.w - m);
        }
        float4 cs = p4;
#pragma unroll
        for (int off = 32; off; off >>= 1) {
            cs.x += __shfl_xor(cs.x, off);
            cs.y += __shfl_xor(cs.y, off);
            cs.z += __shfl_xor(cs.z, off);
            cs.w += __shfl_xor(cs.w, off);
        }
        ssum.x += cs.x; ssum.y += cs.y; ssum.z += cs.z; ssum.w += cs.w;
        *(float4*)&p_lds[wid][lane][0] = p4;
        s_lds[wid][lane] = s_l;

        for (int tt = 0; tt < nc; tt += 8) {
            float w[8]; unsigned off32[8];
#pragma unroll
            for (int j = 0; j < 8; ++j) {
                int idx = tt + j;
                int ic = idx < nc ? idx : 0;
                w[j] = idx < nc ? p_lds[wid][ic][hsel] : 0.f;
                off32[j] = ((unsigned)s_lds[wid][ic] << 9) + lb;
            }
            uint2 u[8];
#pragma unroll
            for (int j = 0; j < 8; ++j)
                u[j] = *(const uint2*)((const char*)zb + off32[j]);
#pragma unroll
            for (int j = 0; j < 8; ++j) {
                f32x2 v01, v23, ww = {w[j], w[j]};
                v01.x = __uint_as_float(u[j].x << 16);
                v01.y = __uint_as_float(u[j].x & 0xffff0000u);
                v23.x = __uint_as_float(u[j].y << 16);
                v23.y = __uint_as_float(u[j].y & 0xffff0000u);
                acc01 = __builtin_elementwise_fma(ww, v01, acc01);
                acc23 = __builtin_elementwise_fma(ww, v23, acc23);
            }
        }
    }
    float4 acc = make_float4(acc01.x, acc01.y, acc23.x, acc23.y);
    float s_h = hsel == 0 ? ssum.x : hsel == 1 ? ssum.y : hsel == 2 ? ssum.z : ssum.w;
    float inv = s_h > 0.f ? 1.f / s_h : 0.f;
    float4 b4 = *(const float4*)(bias + lane * 4);
    float ox = acc.x * inv + b4.x; ox = ox > 0.f ? ox : expm1f(ox);
    float oy = acc.y * inv + b4.y; oy = oy > 0.f ? oy : expm1f(oy);
    float oz = acc.z * inv + b4.z; oz = oz > 0.f ? oz : expm1f(oz);
    float ow = acc.w * inv + b4.w; ow = ow > 0.f ? ow : expm1f(ow);
    ushort4 o;
    o.x = f2bf(ox); o.y = f2bf(oy); o.z = f2bf(oz); o.w = f2bf(ow);
    *(ushort4*)(out + (size_t)n * 256 + lane * 4) = o;
}

// ---------------- layer-2 aggregate (H=1), r7 structure ----------------

__global__ void gat_aggregate_bf(const unsigned short* __restrict__ zb,  // [N,64] bf16
                                 const float* __restrict__ el, const float* __restrict__ er,
                                 const int* __restrict__ rowptr, const int* __restrict__ csr_src,
                                 const float* __restrict__ bias,
                                 float* __restrict__ out, int Nn)
{
    int gw = (blockIdx.x * blockDim.x + threadIdx.x) >> 6;
    int lane = threadIdx.x & 63;
    int n = gw;
    if (n >= Nn) return;
    int start = rowptr[n], end = rowptr[n + 1];
    int deg = end - start;
    float ern = er[n];

    int group = lane >> 4;
    int gl = lane & 15;
    const unsigned lb = (unsigned)(gl << 3);

    f32x2 acc01 = {0.f, 0.f}, acc23 = {0.f, 0.f};
    float m = -INFINITY;
    float ssum = 0.f;

    for (int c0 = 0; c0 < deg; c0 += 64) {
        int nc = min(64, deg - c0);
        int s_l = 0;
        float e_l = -INFINITY;
        if (lane < nc) {
            s_l = csr_src[start + c0 + lane];
            float e = el[s_l] + ern;
            e_l = e > 0.f ? e : 0.2f * e;
        }
        float cm = e_l;
#pragma unroll
        for (int off = 32; off; off >>= 1) cm = fmaxf(cm, __shfl_xor(cm, off));
        float newm = fmaxf(m, cm);
        float scale = __expf(m - newm);
        ssum *= scale;
        f32x2 sc2 = {scale, scale};
        acc01 *= sc2; acc23 *= sc2;
        m = newm;
        float p_l = (lane < nc) ? __expf(e_l - m) : 0.f;
        float cs = p_l;
#pragma unroll
        for (int off = 32; off; off >>= 1) cs += __shfl_xor(cs, off);
        ssum += cs;

        int nIter = (nc + 3) >> 2;
        for (int i0 = 0; i0 < nIter; i0 += 4) {
            float w[4]; unsigned off32[4];
#pragma unroll
            for (int j = 0; j < 4; ++j) {
                int tt = group + 4 * (i0 + j);
                int tc = tt & 63;
                float wv = __shfl(p_l, tc);
                int s = __shfl(s_l, tc);
                w[j] = (tt < nc) ? wv : 0.f;
                off32[j] = ((unsigned)s << 7) + lb;
            }
            uint2 u[4];
#pragma unroll
            for (int j = 0; j < 4; ++j)
                u[j] = *(const uint2*)((const char*)zb + off32[j]);
#pragma unroll
            for (int j = 0; j < 4; ++j) {
                f32x2 v01, v23, ww = {w[j], w[j]};
                v01.x = __uint_as_float(u[j].x << 16);
                v01.y = __uint_as_float(u[j].x & 0xffff0000u);
                v23.x = __uint_as_float(u[j].y << 16);
                v23.y = __uint_as_float(u[j].y & 0xffff0000u);
                acc01 = __builtin_elementwise_fma(ww, v01, acc01);
                acc23 = __builtin_elementwise_fma(ww, v23, acc23);
            }
        }
    }
    float4 acc = make_float4(acc01.x, acc01.y, acc23.x, acc23.y);
#pragma unroll
    for (int off = 16; off <= 32; off <<= 1) {
        acc.x += __shfl_xor(acc.x, off);
        acc.y += __shfl_xor(acc.y, off);
        acc.z += __shfl_xor(acc.z, off);
        acc.w += __shfl_xor(acc.w, off);
    }
    float inv = ssum > 0.f ? 1.f / ssum : 0.f;
    if (lane < 16) {
        float4 o;
        o.x = acc.x * inv + bias[gl * 4 + 0];
        o.y = acc.y * inv + bias[gl * 4 + 1];
        o.z = acc.z * inv + bias[gl * 4 + 2];
        o.w = acc.w * inv + bias[gl * 4 + 3];
        *(float4*)(out + (size_t)n * 64 + gl * 4) = o;
    }
}

// ---------------- launch ----------------

static inline size_t align_up(size_t x, size_t a) { return (x + a - 1) & ~(a - 1); }

extern "C" void kernel_launch(void* const* d_in, const int* in_sizes, int n_in,
                              void* d_out, int out_size, void* d_ws, size_t ws_size,
                              hipStream_t stream) {
    const float* x   = (const float*)d_in[0];
    const float* W1  = (const float*)d_in[1];
    const float* al1 = (const float*)d_in[2];
    const float* ar1 = (const float*)d_in[3];
    const float* b1  = (const float*)d_in[4];
    const float* W2  = (const float*)d_in[5];
    const float* al2 = (const float*)d_in[6];
    const float* ar2 = (const float*)d_in[7];
    const float* b2  = (const float*)d_in[8];
    const int*   src = (const int*)d_in[9];
    const int*   dst = (const int*)d_in[10];
    float* out = (float*)d_out;

    char* ws = (char*)d_ws;
    size_t off = 0;
    unsigned short* zb1 = (unsigned short*)(ws + off); off = align_up(off + (size_t)NN * 256 * 2, 256);
    unsigned short* h1b = (unsigned short*)(ws + off); off = align_up(off + (size_t)NN * 256 * 2, 256);
    unsigned short* zb2 = (unsigned short*)(ws + off); off = align_up(off + (size_t)NN * 64 * 2, 256);
    float* el1 = (float*)(ws + off); off = align_up(off + (size_t)NN * H1 * 4, 256);
    float* er1 = (float*)(ws + off); off = align_up(off + (size_t)NN * H1 * 4, 256);
    float* el2 = (float*)(ws + off); off = align_up(off + (size_t)NN * 4, 256);
    float* er2 = (float*)(ws + off); off = align_up(off + (size_t)NN * 4, 256);
    short* W1th = (short*)(ws + off); off = align_up(off + 256 * 256 * 2, 256);
    short* W1tl = (short*)(ws + off); off = align_up(off + 256 * 256 * 2, 256);
    short* W2th = (short*)(ws + off); off = align_up(off + 64 * 256 * 2, 256);
    short* W2tl = (short*)(ws + off); off = align_up(off + 64 * 256 * 2, 256);
    int* rowptr = (int*)(ws + off); off = align_up(off + (size_t)(NN + 1) * 4, 256);
    int* deg    = (int*)(ws + off); off = align_up(off + (size_t)NN * 4, 256);
    int* fillc  = (int*)(ws + off); off = align_up(off + (size_t)NN * 4, 256);
    int* csr_src = (int*)(ws + off); off = align_up(off + (size_t)EE * 4, 256);

    const int nEdgeBlocks = (EE + 255) / 256;
    const int nMBlocks64 = (NN + 63) / 64;     // 782
    const int nMBlocks128 = (NN + 127) / 128;  // 391

    hipMemsetAsync(deg, 0, (size_t)NN * 4, stream);
    hipMemsetAsync(fillc, 0, (size_t)NN * 4, stream);
    hist_wsplit<<<nEdgeBlocks, 256, 0, stream>>>(dst, deg, EE, W1, W2, W1th, W1tl, W2th, W2tl);
    scan_one<<<1, 1024, 0, stream>>>(deg, rowptr);
    fill_csr<<<nEdgeBlocks, 256, 0, stream>>>(src, dst, rowptr, fillc, csr_src, EE);

    // ---- layer 1: BM=64, BN=256, 3 blocks/CU ----
    gemm_bf16x2<4, 1, 4, 256, 4, true><<<dim3(nMBlocks64, 1), 256, 0, stream>>>(
        x, W1th, W1tl, al1, ar1, zb1, el1, er1, NN, FIN);
    gat_aggregate_h4<<<(NN + 3) / 4, 256, 0, stream>>>(
        zb1, el1, er1, rowptr, csr_src, b1, h1b, NN);

    // ---- layer 2 ----
    gemm_bf16x2<2, 4, 1, 64, 1, false><<<dim3(nMBlocks128, 1), 256, 0, stream>>>(
        h1b, W2th, W2tl, al2, ar2, zb2, el2, er2, NN, H1 * HID);
    gat_aggregate_bf<<<(NN * 64 + 255) / 256, 256, 0, stream>>>(
        zb2, el2, er2, rowptr, csr_src, b2, out, NN);
}

// Round 12
// 211.273 us; speedup vs baseline: 1.4904x; 1.3840x over previous
//
#include <hip/hip_runtime.h>
#include <hip/hip_bf16.h>
#include <math.h>

#define NN 50000
#define EE 800000
#define FIN 256
#define HID 64
#define OUTD 64
#define H1 4
#define H2 1

typedef __attribute__((ext_vector_type(8))) short short8;
typedef __attribute__((ext_vector_type(4))) short short4v;
typedef __attribute__((ext_vector_type(4))) float f32x4;
typedef __attribute__((ext_vector_type(2))) float f32x2;

// ---------------- helpers ----------------

__device__ __forceinline__ unsigned short f2bf(float f) {   // round-to-nearest-even
    unsigned u = __float_as_uint(f);
    unsigned r = (u + 0x7FFFu + ((u >> 16) & 1u)) >> 16;
    return (unsigned short)r;
}
__device__ __forceinline__ float bf2f(unsigned short u) {
    return __uint_as_float(((unsigned)u) << 16);
}

// ---------------- CSR build ----------------
// hist (+ edge rank) + weight split fused. rank[e] = arrival order within dst
// -> fill pass needs no atomics and no fillc buffer.

__global__ void hist_wsplit(const int* __restrict__ dst, int* __restrict__ deg,
                            int* __restrict__ rank, int nE,
                            const float* __restrict__ W1, const float* __restrict__ W2,
                            short* __restrict__ W1th, short* __restrict__ W1tl,
                            short* __restrict__ W2th, short* __restrict__ W2tl) {
    int e = blockIdx.x * 256 + threadIdx.x;
    if (e < nE) rank[e] = atomicAdd(&deg[dst[e]], 1);
    int n = blockIdx.x;
    int k = threadIdx.x;
    if (n < 256) {
        float v = W1[(size_t)k * 256 + n];
        unsigned short hi = f2bf(v);
        unsigned short lo = f2bf(v - bf2f(hi));
        W1th[n * 256 + k] = (short)hi;
        W1tl[n * 256 + k] = (short)lo;
    } else if (n < 320) {
        int n2 = n - 256;
        float v = W2[(size_t)k * 64 + n2];
        unsigned short hi = f2bf(v);
        unsigned short lo = f2bf(v - bf2f(hi));
        W2th[n2 * 256 + k] = (short)hi;
        W2tl[n2 * 256 + k] = (short)lo;
    }
}

// parallel scan chain (r7-proven; each kernel is tiny and multi-block)
__global__ void scan_block(const int* __restrict__ in, int* __restrict__ out,
                           int* __restrict__ bsums, int n) {
    __shared__ int sh[256];
    int i = blockIdx.x * 256 + threadIdx.x;
    int v = (i < n) ? in[i] : 0;
    sh[threadIdx.x] = v;
    __syncthreads();
    for (int off = 1; off < 256; off <<= 1) {
        int t = 0;
        if (threadIdx.x >= off) t = sh[threadIdx.x - off];
        __syncthreads();
        if (threadIdx.x >= off) sh[threadIdx.x] += t;
        __syncthreads();
    }
    if (i < n) out[i] = sh[threadIdx.x] - v;          // exclusive
    if (threadIdx.x == 255) bsums[blockIdx.x] = sh[255];
}

__global__ void scan_bsums(int* __restrict__ bsums, int nb) {
    __shared__ int sh[256];
    int v = (threadIdx.x < nb) ? bsums[threadIdx.x] : 0;
    sh[threadIdx.x] = v;
    __syncthreads();
    for (int off = 1; off < 256; off <<= 1) {
        int t = 0;
        if (threadIdx.x >= off) t = sh[threadIdx.x - off];
        __syncthreads();
        if (threadIdx.x >= off) sh[threadIdx.x] += t;
        __syncthreads();
    }
    if (threadIdx.x < nb) bsums[threadIdx.x] = sh[threadIdx.x] - v;  // exclusive
}

__global__ void add_offsets(int* __restrict__ out, const int* __restrict__ bsums,
                            int n, int Etot) {
    int i = blockIdx.x * 256 + threadIdx.x;
    if (i < n) out[i] += bsums[blockIdx.x];
    if (i == 0) out[n] = Etot;
}

__global__ void fill_csr(const int* __restrict__ src, const int* __restrict__ dst,
                         const int* __restrict__ rowptr, const int* __restrict__ rank,
                         int* __restrict__ csr_src, int nE) {
    int e = blockIdx.x * 256 + threadIdx.x;
    if (e < nE) {
        int pos = rowptr[dst[e]] + rank[e];
        csr_src[pos] = src[e];
    }
}

// ---------------- MFMA GEMM + fused scores epilogue ----------
// ASPLIT=true : A f32, split to hi/lo in staging, 3 MFMA passes.
// ASPLIT=false: A already bf16 (exact), 2 MFMA passes.
// NOTE (r9 lesson): keep LDS <= ~51KB so >=3 blocks/CU.

template<int MF, int WR, int WC, int NT, int H, bool ASPLIT>
__global__ __launch_bounds__(256) void gemm_bf16x2(
    const void* __restrict__ Av, const short* __restrict__ Bth, const short* __restrict__ Btl,
    const float* __restrict__ al, const float* __restrict__ ar,
    unsigned short* __restrict__ zb, float* __restrict__ el, float* __restrict__ er,
    int M, int K)
{
    constexpr int BM = WR * MF * 16;
    constexpr int BN = WC * 64;
    __shared__ short Ah[BM * 40];
    __shared__ short Al[ASPLIT ? BM * 40 : 8];
    __shared__ short Bh[BN * 40], Bl[BN * 40];

    const int bm = blockIdx.x * BM;
    const int bn = blockIdx.y * BN;
    const int t = threadIdx.x;
    const int wid = t >> 6;
    const int lane = t & 63;
    const int lr = lane & 15;
    const int lg = lane >> 4;
    const int wr = wid / WC;
    const int wc = wid % WC;

    f32x4 acc[MF][4];
#pragma unroll
    for (int mf = 0; mf < MF; ++mf)
#pragma unroll
        for (int nf = 0; nf < 4; ++nf) acc[mf][nf] = (f32x4)(0.f);

    for (int k0 = 0; k0 < K; k0 += 32) {
        if constexpr (ASPLIT) {
            const float* A = (const float*)Av;
#pragma unroll
            for (int q = 0; q < BM / 32; ++q) {
                int linear = q * 256 + t;
                int row = linear >> 3;
                int kq = (linear & 7) * 4;
                int grow = bm + row;
                float4 av = make_float4(0.f, 0.f, 0.f, 0.f);
                if (grow < M) av = *(const float4*)(A + (size_t)grow * K + k0 + kq);
                short4v hi, lo;
                unsigned short h0 = f2bf(av.x); hi.x = (short)h0; lo.x = (short)f2bf(av.x - bf2f(h0));
                unsigned short h1v = f2bf(av.y); hi.y = (short)h1v; lo.y = (short)f2bf(av.y - bf2f(h1v));
                unsigned short h2v = f2bf(av.z); hi.z = (short)h2v; lo.z = (short)f2bf(av.z - bf2f(h2v));
                unsigned short h3v = f2bf(av.w); hi.w = (short)h3v; lo.w = (short)f2bf(av.w - bf2f(h3v));
                *(short4v*)&Ah[row * 40 + kq] = hi;
                *(short4v*)&Al[row * 40 + kq] = lo;
            }
        } else {
            const unsigned short* A = (const unsigned short*)Av;
#pragma unroll
            for (int q = 0; q < BM / 64; ++q) {
                int linear = q * 256 + t;
                int row = linear >> 2;
                int k8 = (linear & 3) * 8;
                int grow = bm + row;
                short8 v = (short8)(0);
                if (grow < M) v = *(const short8*)(A + (size_t)grow * K + k0 + k8);
                *(short8*)&Ah[row * 40 + k8] = v;
            }
        }
#pragma unroll
        for (int q = 0; q < BN / 64; ++q) {
            int linear = q * 256 + t;
            int n = linear >> 2;
            int k8 = (linear & 3) * 8;
            short8 vh = *(const short8*)(Bth + (size_t)(bn + n) * K + k0 + k8);
            short8 vl = *(const short8*)(Btl + (size_t)(bn + n) * K + k0 + k8);
            *(short8*)&Bh[n * 40 + k8] = vh;
            *(short8*)&Bl[n * 40 + k8] = vl;
        }
        __syncthreads();

        short8 bh[4], blo[4];
#pragma unroll
        for (int nf = 0; nf < 4; ++nf) {
            int col = wc * 64 + nf * 16 + lr;
            bh[nf]  = *(const short8*)&Bh[col * 40 + lg * 8];
            blo[nf] = *(const short8*)&Bl[col * 40 + lg * 8];
        }
#pragma unroll
        for (int mf = 0; mf < MF; ++mf) {
            int row = wr * MF * 16 + mf * 16 + lr;
            short8 ah = *(const short8*)&Ah[row * 40 + lg * 8];
            short8 alo;
            if constexpr (ASPLIT) alo = *(const short8*)&Al[row * 40 + lg * 8];
#pragma unroll
            for (int nf = 0; nf < 4; ++nf) {
                acc[mf][nf] = __builtin_amdgcn_mfma_f32_16x16x32_bf16(ah, bh[nf],  acc[mf][nf], 0, 0, 0);
                acc[mf][nf] = __builtin_amdgcn_mfma_f32_16x16x32_bf16(ah, blo[nf], acc[mf][nf], 0, 0, 0);
                if constexpr (ASPLIT)
                    acc[mf][nf] = __builtin_amdgcn_mfma_f32_16x16x32_bf16(alo, bh[nf], acc[mf][nf], 0, 0, 0);
            }
        }
        __syncthreads();
    }

    // ---- epilogue: zb (bf16) + el/er ----
    const int h = (bn + wc * 64) >> 6;
    float alv[4], arv[4];
#pragma unroll
    for (int nf = 0; nf < 4; ++nf) {
        alv[nf] = al[h * 64 + nf * 16 + lr];
        arv[nf] = ar[h * 64 + nf * 16 + lr];
    }
#pragma unroll
    for (int mf = 0; mf < MF; ++mf) {
#pragma unroll
        for (int j = 0; j < 4; ++j) {
            int row = bm + wr * MF * 16 + mf * 16 + lg * 4 + j;
            float sel = 0.f, ser = 0.f;
#pragma unroll
            for (int nf = 0; nf < 4; ++nf) {
                float v = acc[mf][nf][j];
                sel += v * alv[nf];
                ser += v * arv[nf];
                if (row < M)
                    zb[(size_t)row * NT + bn + wc * 64 + nf * 16 + lr] = f2bf(v);
            }
#pragma unroll
            for (int off = 1; off <= 8; off <<= 1) {
                sel += __shfl_xor(sel, off);
                ser += __shfl_xor(ser, off);
            }
            if (lr == 0 && row < M) {
                el[(size_t)row * H + h] = sel;
                er[(size_t)row * H + h] = ser;
            }
        }
    }
}

// ---------------- layer-1 aggregate (r7 structure: best measured) ----------------

__global__ __launch_bounds__(256) void gat_aggregate_h4(
    const unsigned short* __restrict__ zb,   // [N,256] bf16
    const float* __restrict__ el,            // [N,4]
    const float* __restrict__ er,            // [N,4]
    const int* __restrict__ rowptr, const int* __restrict__ csr_src,
    const float* __restrict__ bias,          // [256]
    unsigned short* __restrict__ out,        // [N,256] bf16 (ELU applied)
    int Nn)
{
    __shared__ float p_lds[4][64][4];
    __shared__ int   s_lds[4][64];
    int wid = threadIdx.x >> 6;
    int lane = threadIdx.x & 63;
    int n = blockIdx.x * 4 + wid;
    if (n >= Nn) return;
    int start = rowptr[n], end = rowptr[n + 1];
    int deg = end - start;
    float4 er4 = *(const float4*)(er + (size_t)n * 4);
    int hsel = lane >> 4;
    const unsigned lb = (unsigned)(lane << 3);   // byte offset of this lane in a 512B row

    f32x2 acc01 = {0.f, 0.f}, acc23 = {0.f, 0.f};
    float4 ssum = make_float4(0.f, 0.f, 0.f, 0.f);
    float m = -INFINITY;

    for (int c0 = 0; c0 < deg; c0 += 64) {
        int nc = min(64, deg - c0);
        int s_l = 0;
        float4 e4 = make_float4(-INFINITY, -INFINITY, -INFINITY, -INFINITY);
        float emax_l = -INFINITY;
        if (lane < nc) {
            s_l = csr_src[start + c0 + lane];
            float4 el4 = *(const float4*)(el + (size_t)s_l * 4);
            e4.x = el4.x + er4.x; e4.x = e4.x > 0.f ? e4.x : 0.2f * e4.x;
            e4.y = el4.y + er4.y; e4.y = e4.y > 0.f ? e4.y : 0.2f * e4.y;
            e4.z = el4.z + er4.z; e4.z = e4.z > 0.f ? e4.z : 0.2f * e4.z;
            e4.w = el4.w + er4.w; e4.w = e4.w > 0.f ? e4.w : 0.2f * e4.w;
            emax_l = fmaxf(fmaxf(e4.x, e4.y), fmaxf(e4.z, e4.w));
        }
        float cm = emax_l;
#pragma unroll
        for (int off = 32; off; off >>= 1) cm = fmaxf(cm, __shfl_xor(cm, off));
        float newm = fmaxf(m, cm);
        float scale = __expf(m - newm);
        ssum.x *= scale; ssum.y *= scale; ssum.z *= scale; ssum.w *= scale;
        f32x2 sc2 = {scale, scale};
        acc01 *= sc2; acc23 *= sc2;
        m = newm;
        float4 p4 = make_float4(0.f, 0.f, 0.f, 0.f);
        if (lane < nc) {
            p4.x = __expf(e4.x - m);
            p4.y = __expf(e4.y - m);
            p4.z = __expf(e4.z - m);
            p4.w = __expf(e4.w - m);
        }
        float4 cs = p4;
#pragma unroll
        for (int off = 32; off; off >>= 1) {
            cs.x += __shfl_xor(cs.x, off);
            cs.y += __shfl_xor(cs.y, off);
            cs.z += __shfl_xor(cs.z, off);
            cs.w += __shfl_xor(cs.w, off);
        }
        ssum.x += cs.x; ssum.y += cs.y; ssum.z += cs.z; ssum.w += cs.w;
        *(float4*)&p_lds[wid][lane][0] = p4;
        s_lds[wid][lane] = s_l;

        for (int tt = 0; tt < nc; tt += 8) {
            float w[8]; unsigned off32[8];
#pragma unroll
            for (int j = 0; j < 8; ++j) {
                int idx = tt + j;
                int ic = idx < nc ? idx : 0;
                w[j] = idx < nc ? p_lds[wid][ic][hsel] : 0.f;
                off32[j] = ((unsigned)s_lds[wid][ic] << 9) + lb;
            }
            uint2 u[8];
#pragma unroll
            for (int j = 0; j < 8; ++j)
                u[j] = *(const uint2*)((const char*)zb + off32[j]);
#pragma unroll
            for (int j = 0; j < 8; ++j) {
                f32x2 v01, v23, ww = {w[j], w[j]};
                v01.x = __uint_as_float(u[j].x << 16);
                v01.y = __uint_as_float(u[j].x & 0xffff0000u);
                v23.x = __uint_as_float(u[j].y << 16);
                v23.y = __uint_as_float(u[j].y & 0xffff0000u);
                acc01 = __builtin_elementwise_fma(ww, v01, acc01);
                acc23 = __builtin_elementwise_fma(ww, v23, acc23);
            }
        }
    }
    float4 acc = make_float4(acc01.x, acc01.y, acc23.x, acc23.y);
    float s_h = hsel == 0 ? ssum.x : hsel == 1 ? ssum.y : hsel == 2 ? ssum.z : ssum.w;
    float inv = s_h > 0.f ? 1.f / s_h : 0.f;
    float4 b4 = *(const float4*)(bias + lane * 4);
    float ox = acc.x * inv + b4.x; ox = ox > 0.f ? ox : expm1f(ox);
    float oy = acc.y * inv + b4.y; oy = oy > 0.f ? oy : expm1f(oy);
    float oz = acc.z * inv + b4.z; oz = oz > 0.f ? oz : expm1f(oz);
    float ow = acc.w * inv + b4.w; ow = ow > 0.f ? ow : expm1f(ow);
    ushort4 o;
    o.x = f2bf(ox); o.y = f2bf(oy); o.z = f2bf(oz); o.w = f2bf(ow);
    *(ushort4*)(out + (size_t)n * 256 + lane * 4) = o;
}

// ---------------- layer-2 aggregate (H=1), r7 structure ----------------

__global__ void gat_aggregate_bf(const unsigned short* __restrict__ zb,  // [N,64] bf16
                                 const float* __restrict__ el, const float* __restrict__ er,
                                 const int* __restrict__ rowptr, const int* __restrict__ csr_src,
                                 const float* __restrict__ bias,
                                 float* __restrict__ out, int Nn)
{
    int gw = (blockIdx.x * blockDim.x + threadIdx.x) >> 6;
    int lane = threadIdx.x & 63;
    int n = gw;
    if (n >= Nn) return;
    int start = rowptr[n], end = rowptr[n + 1];
    int deg = end - start;
    float ern = er[n];

    int group = lane >> 4;
    int gl = lane & 15;
    const unsigned lb = (unsigned)(gl << 3);

    f32x2 acc01 = {0.f, 0.f}, acc23 = {0.f, 0.f};
    float m = -INFINITY;
    float ssum = 0.f;

    for (int c0 = 0; c0 < deg; c0 += 64) {
        int nc = min(64, deg - c0);
        int s_l = 0;
        float e_l = -INFINITY;
        if (lane < nc) {
            s_l = csr_src[start + c0 + lane];
            float e = el[s_l] + ern;
            e_l = e > 0.f ? e : 0.2f * e;
        }
        float cm = e_l;
#pragma unroll
        for (int off = 32; off; off >>= 1) cm = fmaxf(cm, __shfl_xor(cm, off));
        float newm = fmaxf(m, cm);
        float scale = __expf(m - newm);
        ssum *= scale;
        f32x2 sc2 = {scale, scale};
        acc01 *= sc2; acc23 *= sc2;
        m = newm;
        float p_l = (lane < nc) ? __expf(e_l - m) : 0.f;
        float cs = p_l;
#pragma unroll
        for (int off = 32; off; off >>= 1) cs += __shfl_xor(cs, off);
        ssum += cs;

        int nIter = (nc + 3) >> 2;
        for (int i0 = 0; i0 < nIter; i0 += 4) {
            float w[4]; unsigned off32[4];
#pragma unroll
            for (int j = 0; j < 4; ++j) {
                int tt = group + 4 * (i0 + j);
                int tc = tt & 63;
                float wv = __shfl(p_l, tc);
                int s = __shfl(s_l, tc);
                w[j] = (tt < nc) ? wv : 0.f;
                off32[j] = ((unsigned)s << 7) + lb;
            }
            uint2 u[4];
#pragma unroll
            for (int j = 0; j < 4; ++j)
                u[j] = *(const uint2*)((const char*)zb + off32[j]);
#pragma unroll
            for (int j = 0; j < 4; ++j) {
                f32x2 v01, v23, ww = {w[j], w[j]};
                v01.x = __uint_as_float(u[j].x << 16);
                v01.y = __uint_as_float(u[j].x & 0xffff0000u);
                v23.x = __uint_as_float(u[j].y << 16);
                v23.y = __uint_as_float(u[j].y & 0xffff0000u);
                acc01 = __builtin_elementwise_fma(ww, v01, acc01);
                acc23 = __builtin_elementwise_fma(ww, v23, acc23);
            }
        }
    }
    float4 acc = make_float4(acc01.x, acc01.y, acc23.x, acc23.y);
#pragma unroll
    for (int off = 16; off <= 32; off <<= 1) {
        acc.x += __shfl_xor(acc.x, off);
        acc.y += __shfl_xor(acc.y, off);
        acc.z += __shfl_xor(acc.z, off);
        acc.w += __shfl_xor(acc.w, off);
    }
    float inv = ssum > 0.f ? 1.f / ssum : 0.f;
    if (lane < 16) {
        float4 o;
        o.x = acc.x * inv + bias[gl * 4 + 0];
        o.y = acc.y * inv + bias[gl * 4 + 1];
        o.z = acc.z * inv + bias[gl * 4 + 2];
        o.w = acc.w * inv + bias[gl * 4 + 3];
        *(float4*)(out + (size_t)n * 64 + gl * 4) = o;
    }
}

// ---------------- launch ----------------

static inline size_t align_up(size_t x, size_t a) { return (x + a - 1) & ~(a - 1); }

extern "C" void kernel_launch(void* const* d_in, const int* in_sizes, int n_in,
                              void* d_out, int out_size, void* d_ws, size_t ws_size,
                              hipStream_t stream) {
    const float* x   = (const float*)d_in[0];
    const float* W1  = (const float*)d_in[1];
    const float* al1 = (const float*)d_in[2];
    const float* ar1 = (const float*)d_in[3];
    const float* b1  = (const float*)d_in[4];
    const float* W2  = (const float*)d_in[5];
    const float* al2 = (const float*)d_in[6];
    const float* ar2 = (const float*)d_in[7];
    const float* b2  = (const float*)d_in[8];
    const int*   src = (const int*)d_in[9];
    const int*   dst = (const int*)d_in[10];
    float* out = (float*)d_out;

    char* ws = (char*)d_ws;
    size_t off = 0;
    unsigned short* zb1 = (unsigned short*)(ws + off); off = align_up(off + (size_t)NN * 256 * 2, 256);
    unsigned short* h1b = (unsigned short*)(ws + off); off = align_up(off + (size_t)NN * 256 * 2, 256);
    unsigned short* zb2 = (unsigned short*)(ws + off); off = align_up(off + (size_t)NN * 64 * 2, 256);
    float* el1 = (float*)(ws + off); off = align_up(off + (size_t)NN * H1 * 4, 256);
    float* er1 = (float*)(ws + off); off = align_up(off + (size_t)NN * H1 * 4, 256);
    float* el2 = (float*)(ws + off); off = align_up(off + (size_t)NN * 4, 256);
    float* er2 = (float*)(ws + off); off = align_up(off + (size_t)NN * 4, 256);
    short* W1th = (short*)(ws + off); off = align_up(off + 256 * 256 * 2, 256);
    short* W1tl = (short*)(ws + off); off = align_up(off + 256 * 256 * 2, 256);
    short* W2th = (short*)(ws + off); off = align_up(off + 64 * 256 * 2, 256);
    short* W2tl = (short*)(ws + off); off = align_up(off + 64 * 256 * 2, 256);
    int* rowptr = (int*)(ws + off); off = align_up(off + (size_t)(NN + 1) * 4, 256);
    int* deg    = (int*)(ws + off); off = align_up(off + (size_t)NN * 4, 256);
    int* rank   = (int*)(ws + off); off = align_up(off + (size_t)EE * 4, 256);
    int* bsums  = (int*)(ws + off); off = align_up(off + 256 * 4, 256);
    int* csr_src = (int*)(ws + off); off = align_up(off + (size_t)EE * 4, 256);

    const int nScanBlocks = (NN + 255) / 256;  // 196
    const int nEdgeBlocks = (EE + 255) / 256;  // 3125
    const int nMBlocks64 = (NN + 63) / 64;     // 782
    const int nMBlocks128 = (NN + 127) / 128;  // 391

    hipMemsetAsync(deg, 0, (size_t)NN * 4, stream);
    hist_wsplit<<<nEdgeBlocks, 256, 0, stream>>>(dst, deg, rank, EE,
                                                 W1, W2, W1th, W1tl, W2th, W2tl);
    scan_block<<<nScanBlocks, 256, 0, stream>>>(deg, rowptr, bsums, NN);
    scan_bsums<<<1, 256, 0, stream>>>(bsums, nScanBlocks);
    add_offsets<<<nScanBlocks, 256, 0, stream>>>(rowptr, bsums, NN, EE);
    fill_csr<<<nEdgeBlocks, 256, 0, stream>>>(src, dst, rowptr, rank, csr_src, EE);

    // ---- layer 1: BM=64, BN=256, 3 blocks/CU ----
    gemm_bf16x2<4, 1, 4, 256, 4, true><<<dim3(nMBlocks64, 1), 256, 0, stream>>>(
        x, W1th, W1tl, al1, ar1, zb1, el1, er1, NN, FIN);
    gat_aggregate_h4<<<(NN + 3) / 4, 256, 0, stream>>>(
        zb1, el1, er1, rowptr, csr_src, b1, h1b, NN);

    // ---- layer 2 ----
    gemm_bf16x2<2, 4, 1, 64, 1, false><<<dim3(nMBlocks128, 1), 256, 0, stream>>>(
        h1b, W2th, W2tl, al2, ar2, zb2, el2, er2, NN, H1 * HID);
    gat_aggregate_bf<<<(NN * 64 + 255) / 256, 256, 0, stream>>>(
        zb2, el2, er2, rowptr, csr_src, b2, out, NN);
}